// Round 7
// baseline (424.523 us; speedup 1.0000x reference)
//
#include <hip/hip_runtime.h>
#include <hip/hip_bf16.h>

// Problem constants (HumanVAttention: B=2,T=4096,HID=2048,H=16,HKV=4,D=128,
// ROT=64, BLK=64, LOCAL=8, GLOB=1).
// DTYPE (established empirically): harness presents ALL tensors in f32.
// Internal compute bf16 MFMA; I/O f32. Threshold is bf16-grade.
#define Hq   16
#define HKV  4
#define Dh   128
#define ROT  64
#define BLKQ 64
#define NBLK 64      // T/BLK
#define Tlen 4096
#define Bsz  2
#define HID  2048
#define QKVC 3072    // 2048 q + 512 k + 512 v
#define SCALE_C 0.08838834764831845f

typedef __attribute__((ext_vector_type(8))) short bf16x8;
typedef __attribute__((ext_vector_type(4))) float f32x4;
typedef __attribute__((ext_vector_type(4))) unsigned short u16x4;

#define MFMA16(a, b, c) __builtin_amdgcn_mfma_f32_16x16x32_bf16((a), (b), (c), 0, 0, 0)

__device__ __forceinline__ void async_copy16(__hip_bfloat16* lds, const __hip_bfloat16* g) {
    __builtin_amdgcn_global_load_lds(
        (const __attribute__((address_space(1))) void*)g,
        (__attribute__((address_space(3))) void*)lds,
        16, 0, 0);
}

// f32 -> bf16 bulk convert. blockIdx.y selects tensor {hs, Wq, Wk, Wv, Wo}.
__global__ __launch_bounds__(256) void cvt_kernel(
    const float* __restrict__ s0, const float* __restrict__ s1,
    const float* __restrict__ s2, const float* __restrict__ s3,
    const float* __restrict__ s4,
    __hip_bfloat16* __restrict__ base,
    int n0, int n1, int n2, int n3, int n4)
{
    const float* src;
    size_t off, n;
    switch (blockIdx.y) {
        case 0:  src = s0; off = 0;                          n = n0; break;
        case 1:  src = s1; off = (size_t)n0;                 n = n1; break;
        case 2:  src = s2; off = (size_t)n0 + n1;            n = n2; break;
        case 3:  src = s3; off = (size_t)n0 + n1 + n2;       n = n3; break;
        default: src = s4; off = (size_t)n0 + n1 + n2 + n3;  n = n4; break;
    }
    __hip_bfloat16* dst = base + off;
    const size_t stride = (size_t)gridDim.x * 2048;
    for (size_t i = ((size_t)blockIdx.x * 256 + threadIdx.x) * 8; i < n; i += stride) {
        const float4 a = *(const float4*)(src + i);
        const float4 b = *(const float4*)(src + i + 4);
        union { bf16x8 v; __hip_bfloat16 e[8]; } u;
        u.e[0] = __float2bfloat16(a.x); u.e[1] = __float2bfloat16(a.y);
        u.e[2] = __float2bfloat16(a.z); u.e[3] = __float2bfloat16(a.w);
        u.e[4] = __float2bfloat16(b.x); u.e[5] = __float2bfloat16(b.y);
        u.e[6] = __float2bfloat16(b.z); u.e[7] = __float2bfloat16(b.w);
        *(bf16x8*)(dst + i) = u.v;
    }
}

// C[M,N] = A[M,K] * B[N,K]^T, bf16 in. 128x128 tile, BK=64, 4 waves, 256 thr,
// double-buffered 64 KiB LDS => 2 independent blocks/CU. Eager-stage: tile u
// stages tile u+2 into buf[P] (the buffer tile u just read) after bar1
// certifies all reads are in registers; vmcnt(8) at the boundary waits on
// loads issued two tiles ago (never drains to 0 in the main loop).
//
// ROUND-7 CHANGE — k0/k1 MFMA split around bar1:
// R4/R6 forced lgkmcnt(0)+bar1 BEFORE any MFMA -> full 16-read issue+latency
// (~220 cy) exposed on every tile ahead of the 155-cy MFMA burst (44% util).
// Now: issue k0 frag reads first, then k1 reads; MFMA k0 runs under the
// compiler's partial lgkmcnt (waits only its own 8 reads, k1 latency hidden);
// the explicit lgkmcnt(0) lands AFTER 16 MFMAs (nearly free), bar1 still
// certifies all-reads-in-registers before the eager stage overwrites buf[P];
// MFMA k1 overlaps the stage issue. Sync invariants identical to R4.
template <bool ROPE_, bool F32OUT>
__global__ __launch_bounds__(256, 2) void gemm128db(
    const __hip_bfloat16* __restrict__ A,
    const __hip_bfloat16* __restrict__ B0,
    const __hip_bfloat16* __restrict__ B1,
    const __hip_bfloat16* __restrict__ B2,
    int n1c, int n2c,
    void* __restrict__ C,
    int M, int N, int K,
    const float* __restrict__ cosb,
    const float* __restrict__ sinb)
{
    __shared__ __align__(16) __hip_bfloat16 As[2][128 * 64];
    __shared__ __align__(16) __hip_bfloat16 Bs[2][128 * 64];

    const int m0 = blockIdx.y * 128;
    const int n0 = blockIdx.x * 128;
    const __hip_bfloat16* Bp;
    int nb;
    if (n0 < n1c)      { Bp = B0; nb = n0; }
    else if (n0 < n2c) { Bp = B1; nb = n0 - n1c; }
    else               { Bp = B2; nb = n0 - n2c; }

    const int tid  = threadIdx.x;
    const int lane = tid & 63;
    const int w    = tid >> 6;          // wave 0..3
    const int wm   = (w >> 1) * 64;
    const int wn   = (w & 1) * 64;
    const int lr   = lane >> 3;         // row within 8-row staging group
    const int lc   = lane & 7;          // chunk slot
    const int m16  = lane & 15;
    const int q8   = lane >> 4;
    const int NT   = K >> 6;            // 32 here (>= 3 assumed)

    f32x4 acc[4][4] = {};

    auto stageA = [&](int buf, int kc) {
        #pragma unroll
        for (int ii = 0; ii < 4; ++ii) {
            const int r8 = w * 32 + ii * 8;
            const int r  = r8 + lr;
            const int cg = lc ^ (r & 7);
            async_copy16(&As[buf][r8 * 64], A + (size_t)(m0 + r) * K + kc + cg * 8);
        }
    };
    auto stageB = [&](int buf, int kc) {
        #pragma unroll
        for (int ii = 0; ii < 4; ++ii) {
            const int r8 = w * 32 + ii * 8;
            const int r  = r8 + lr;
            const int cg = lc ^ (r & 7);
            async_copy16(&Bs[buf][r8 * 64], Bp + (size_t)(nb + r) * K + kc + cg * 8);
        }
    };

    // Prologue: tile0 -> buf0 (8 loads/thread), tile1 -> buf1 (8 loads).
    // vmcnt(8) = tile0 complete, tile1 may still fly.
    stageA(0, 0);
    stageB(0, 0);
    stageA(1, 64);
    stageB(1, 64);
    asm volatile("s_waitcnt vmcnt(8)" ::: "memory");
    __builtin_amdgcn_s_barrier();

    for (int u = 0; u < NT; ++u) {
        const int P  = u & 1;
        const __hip_bfloat16* Ap_ = As[P];
        const __hip_bfloat16* Bq_ = Bs[P];

        bf16x8 a0[4], b0[4], a1[4], b1[4];
        // k0 frag reads FIRST (cs = q8) ...
        #pragma unroll
        for (int t = 0; t < 4; ++t) {
            const int row = wm + t * 16 + m16;
            const int col = wn + t * 16 + m16;
            a0[t] = *(const bf16x8*)&Ap_[row * 64 + ((q8) ^ (row & 7)) * 8];
            b0[t] = *(const bf16x8*)&Bq_[col * 64 + ((q8) ^ (col & 7)) * 8];
        }
        // ... then k1 frag reads (cs = 4+q8)
        #pragma unroll
        for (int t = 0; t < 4; ++t) {
            const int row = wm + t * 16 + m16;
            const int col = wn + t * 16 + m16;
            a1[t] = *(const bf16x8*)&Ap_[row * 64 + ((4 + q8) ^ (row & 7)) * 8];
            b1[t] = *(const bf16x8*)&Bq_[col * 64 + ((4 + q8) ^ (col & 7)) * 8];
        }

        // MFMA k0: compiler's partial lgkmcnt waits only a0/b0; the 8 k1
        // reads land underneath this cluster.
        __builtin_amdgcn_s_setprio(1);
        #pragma unroll
        for (int i = 0; i < 4; ++i)
            #pragma unroll
            for (int j = 0; j < 4; ++j)
                acc[i][j] = MFMA16(a0[i], b0[j], acc[i][j]);
        __builtin_amdgcn_s_setprio(0);

        // All 16 reads of buf[P] now in regs (lgkm0 nearly free after 16 MFMA).
        asm volatile("s_waitcnt lgkmcnt(0)" ::: "memory");
        __builtin_amdgcn_sched_barrier(0);
        __builtin_amdgcn_s_barrier();            // bar1: block done reading buf[P]
        __builtin_amdgcn_sched_barrier(0);       // keep stages below bar1

        if (u + 2 < NT) {                        // eager-stage tile u+2 -> buf[P]
            stageA(P, (u + 2) << 6);
            stageB(P, (u + 2) << 6);
        }

        // MFMA k1 overlaps the stage issue.
        __builtin_amdgcn_s_setprio(1);
        #pragma unroll
        for (int i = 0; i < 4; ++i)
            #pragma unroll
            for (int j = 0; j < 4; ++j)
                acc[i][j] = MFMA16(a1[i], b1[j], acc[i][j]);
        __builtin_amdgcn_s_setprio(0);

        // Tile boundary: need tile u+1 (issued two tiles ago) complete.
        if (u + 2 < NT) {
            asm volatile("s_waitcnt vmcnt(8)" ::: "memory");
        } else {
            asm volatile("s_waitcnt vmcnt(0)" ::: "memory");
        }
        __builtin_amdgcn_s_barrier();            // bar2: buf[P^1] ready for tile u+1
    }

    // Fused RoPE: q/k head tiles (n0 < n2c == 2560), rot half (wn == 0).
    if (ROPE_ && n0 < n2c && wn == 0) {
        #pragma unroll
        for (int i = 0; i < 4; ++i)
            #pragma unroll
            for (int r = 0; r < 4; ++r) {
                const int bt = m0 + wm + i * 16 + q8 * 4 + r;   // b*T + t
                #pragma unroll
                for (int j = 0; j < 2; ++j) {
                    const int d = j * 16 + m16;
                    const float c = cosb[(size_t)bt * ROT + d];
                    const float s = sinb[(size_t)bt * ROT + d];
                    const float x1 = acc[i][j][r];
                    const float x2 = acc[i][j + 2][r];
                    acc[i][j][r]     = x1 * c - x2 * s;
                    acc[i][j + 2][r] = x2 * c + x1 * s;
                }
            }
    }

    // epilogue: C layout col=lane&15, row=(lane>>4)*4+reg
    #pragma unroll
    for (int i = 0; i < 4; ++i)
        #pragma unroll
        for (int j = 0; j < 4; ++j)
            #pragma unroll
            for (int r = 0; r < 4; ++r) {
                const int row = m0 + wm + i * 16 + q8 * 4 + r;
                const int col = n0 + wn + j * 16 + m16;
                if (F32OUT)
                    ((float*)C)[(size_t)row * N + col] = acc[i][j][r];
                else
                    ((__hip_bfloat16*)C)[(size_t)row * N + col] =
                        __float2bfloat16(acc[i][j][r]);
            }
}

// V pre-transpose: qkv V block [b][t][kvh][d] -> VTg[(b*4+kvh)*128 + d][t]
// (d-major, bf16). Done ONCE so attn stages V^T with vector writes.
__global__ __launch_bounds__(256) void vtrans_kernel(
    const __hip_bfloat16* __restrict__ qkv,
    __hip_bfloat16* __restrict__ vtg)
{
    const int tb = blockIdx.x;   // t block of 64 (0..63)
    const int pr = blockIdx.y;   // b*4 + kvh (0..7)
    const __hip_bfloat16* src =
        qkv + ((size_t)(pr >> 2) * Tlen + tb * 64) * QKVC + HID + 512 + (pr & 3) * Dh;
    __hip_bfloat16* dst = vtg + (size_t)pr * Dh * Tlen + tb * 64;
    const int tid = threadIdx.x;
    #pragma unroll
    for (int t2 = 0; t2 < 4; ++t2) {
        const int c  = tid + t2 * 256;   // 0..1023: d = c>>3, t0 = (c&7)*8
        const int d  = c >> 3;
        const int t0 = (c & 7) * 8;
        union { bf16x8 v; __hip_bfloat16 e[8]; } u;
        #pragma unroll
        for (int j = 0; j < 8; ++j)
            u.e[j] = src[(size_t)(t0 + j) * QKVC + d];
        *(bf16x8*)(dst + (size_t)d * Tlen + t0) = u.v;
    }
}

// Block-sparse flash attention. Grid (qblock=64, head=16, batch=2), 256 thr.
// Swapped QK^T + in-register softmax (R6-verified). UNCHANGED in R7 —
// awaiting counters (will surface in top-5 once gemms drop below it).
__global__ __launch_bounds__(256, 3) void attn_kernel(
    const __hip_bfloat16* __restrict__ qkv,
    const __hip_bfloat16* __restrict__ vtg,
    __hip_bfloat16* __restrict__ outb)
{
    const int i   = blockIdx.x;   // q block
    const int h   = blockIdx.y;
    const int b   = blockIdx.z;
    const int kvh = h >> 2;
    const int tid  = threadIdx.x;
    const int lane = tid & 63;
    const int w    = tid >> 6;
    const int m16  = lane & 15;
    const int q8   = lane >> 4;

    __shared__ __align__(16) __hip_bfloat16 Ks[64 * 136];   // K rows, 272B stride
    __shared__ __align__(16) __hip_bfloat16 VT[128 * 64];   // V^T, XOR-swizzled chunks
    __shared__ __align__(16) __hip_bfloat16 Pb[4][16 * 64]; // per-wave P, XOR-swizzled

    // Q fragments: row = lane&15 (+w*16), k-chunk = (lane>>4)*8 (B-frag now)
    bf16x8 qf[4];
    {
        const __hip_bfloat16* qp =
            qkv + (size_t)(b * Tlen + i * BLKQ + w * 16 + m16) * QKVC + h * Dh + q8 * 8;
        for (int ks = 0; ks < 4; ++ks) qf[ks] = *(const bf16x8*)(qp + ks * 32);
    }

    f32x4 o[8] = {};                 // O^T: o[dt][r] = O[m16][dt*16+q8*4+r]
    float mrow = -1e30f, lrow = 0.f; // per-lane scalars (lane's q-row = w*16+m16)

    const int nsel = (i + 1 < 9) ? (i + 1) : 9;
    auto kb_of = [&](int j) { return (i <= 7) ? j : ((j == 0) ? 0 : (i - 8 + j)); };

    const __hip_bfloat16* vtbase = vtg + (size_t)(b * HKV + kvh) * Dh * Tlen;

    // Prefetch tile 0 into registers.
    bf16x8 kr[4], vr[4];
    {
        const int kb0 = kb_of(0);
        const __hip_bfloat16* kbase =
            qkv + (size_t)(b * Tlen + kb0 * BLKQ) * QKVC + HID + kvh * Dh;
        #pragma unroll
        for (int t = 0; t < 4; ++t) {
            const int c = tid + t * 256;
            kr[t] = *(const bf16x8*)(kbase + (size_t)(c >> 4) * QKVC + (c & 15) * 8);
            vr[t] = *(const bf16x8*)(vtbase + (size_t)(c >> 3) * Tlen
                                     + kb0 * BLKQ + (c & 7) * 8);
        }
    }

    for (int j = 0; j < nsel; ++j) {
        const int kb = kb_of(j);

        __syncthreads();  // prev iter's LDS reads (Ks/VT/Pb) complete
        // K: row-major vector writes (b128)
        #pragma unroll
        for (int t = 0; t < 4; ++t) {
            const int c = tid + t * 256;
            *(bf16x8*)&Ks[(c >> 4) * 136 + (c & 15) * 8] = kr[t];
        }
        // V^T: vector writes, XOR chunk swizzle (phys chunk = (c&7) ^ (row&7))
        #pragma unroll
        for (int t = 0; t < 4; ++t) {
            const int c = tid + t * 256;
            const int row = c >> 3;
            *(bf16x8*)&VT[row * 64 + (((c & 7) ^ (row & 7)) << 3)] = vr[t];
        }
        __syncthreads();  // staging visible

        // T14: issue next tile's loads now; consumed after next barrier.
        if (j + 1 < nsel) {
            const int kbn = kb_of(j + 1);
            const __hip_bfloat16* kbase =
                qkv + (size_t)(b * Tlen + kbn * BLKQ) * QKVC + HID + kvh * Dh;
            #pragma unroll
            for (int t = 0; t < 4; ++t) {
                const int c = tid + t * 256;
                kr[t] = *(const bf16x8*)(kbase + (size_t)(c >> 4) * QKVC + (c & 15) * 8);
                vr[t] = *(const bf16x8*)(vtbase + (size_t)(c >> 3) * Tlen
                                         + kbn * BLKQ + (c & 7) * 8);
            }
        }

        // S^T = (Q K^T)^T * scale: mfma(A=K, B=Q). Lane holds S[key][qrow]
        // for key = nt*16 + q8*4 + r, qrow = w*16 + m16.
        float sv[4][4];
        __builtin_amdgcn_s_setprio(1);
        for (int nt = 0; nt < 4; ++nt) {
            f32x4 s = {0.f, 0.f, 0.f, 0.f};
            for (int ks = 0; ks < 4; ++ks) {
                bf16x8 kf = *(const bf16x8*)&Ks[(nt * 16 + m16) * 136 + ks * 32 + q8 * 8];
                s = MFMA16(kf, qf[ks], s);
            }
            for (int r = 0; r < 4; ++r) sv[nt][r] = s[r] * SCALE_C;
        }
        __builtin_amdgcn_s_setprio(0);
        if (kb == i) {  // causal mask on self block: key > q-row-in-block
            const int qr = w * 16 + m16;
            #pragma unroll
            for (int nt = 0; nt < 4; ++nt)
                #pragma unroll
                for (int r = 0; r < 4; ++r)
                    if (nt * 16 + q8 * 4 + r > qr) sv[nt][r] = -1e9f;
        }

        // online softmax: in-register 16-way reduce + 2 shfl_xor across q8 dups
        float mx = sv[0][0];
        #pragma unroll
        for (int nt = 0; nt < 4; ++nt)
            #pragma unroll
            for (int r = 0; r < 4; ++r) mx = fmaxf(mx, sv[nt][r]);
        mx = fmaxf(mx, __shfl_xor(mx, 16, 64));
        mx = fmaxf(mx, __shfl_xor(mx, 32, 64));
        const float newm = fmaxf(mrow, mx);
        const float alpha = __expf(mrow - newm);
        mrow = newm;
        float rs = 0.f;
        #pragma unroll
        for (int nt = 0; nt < 4; ++nt)
            #pragma unroll
            for (int r = 0; r < 4; ++r) {
                const float p = __expf(sv[nt][r] - newm);
                sv[nt][r] = p;
                rs += p;
            }
        rs += __shfl_xor(rs, 16, 64);
        rs += __shfl_xor(rs, 32, 64);
        lrow = lrow * alpha + rs;

        // P: per nt, 4 consecutive keys -> one b64 write (XOR-swizzled).
        __hip_bfloat16* Pw = &Pb[w][0];
        #pragma unroll
        for (int nt = 0; nt < 4; ++nt) {
            union { u16x4 v; __hip_bfloat16 e[4]; } u;
            u.e[0] = __float2bfloat16(sv[nt][0]);
            u.e[1] = __float2bfloat16(sv[nt][1]);
            u.e[2] = __float2bfloat16(sv[nt][2]);
            u.e[3] = __float2bfloat16(sv[nt][3]);
            const int chunk = (nt * 2 + (q8 >> 1)) ^ (m16 & 7);
            *(u16x4*)&Pw[m16 * 64 + (chunk << 3) + ((q8 & 1) << 2)] = u.v;
        }

        #pragma unroll
        for (int dt = 0; dt < 8; ++dt)
            #pragma unroll
            for (int r = 0; r < 4; ++r)
                o[dt][r] *= alpha;

        // P writes/reads are same-wave (Pb[w]): drain DS queue, pin order.
        asm volatile("s_waitcnt lgkmcnt(0)" ::: "memory");
        __builtin_amdgcn_sched_barrier(0);

        // O^T += V^T P^T : mfma(A=V^T, B=P); k = 64 keys, 2 k-steps; 8 d-tiles
        __builtin_amdgcn_s_setprio(1);
        for (int kk = 0; kk < 2; ++kk) {
            const int co = ((kk * 4 + q8) ^ (m16 & 7)) << 3;   // swizzled chunk
            bf16x8 pf = *(const bf16x8*)&Pw[m16 * 64 + co];
            #pragma unroll
            for (int dt = 0; dt < 8; ++dt) {
                bf16x8 vf = *(const bf16x8*)&VT[(dt * 16 + m16) * 64 + co];
                o[dt] = MFMA16(vf, pf, o[dt]);
            }
        }
        __builtin_amdgcn_s_setprio(0);
    }

    // epilogue: O^T * (1/l) -> attn buffer [B*T][H*D] (bf16), 8B stores
    const float rcp = 1.0f / lrow;
    __hip_bfloat16* op = outb + (size_t)(b * Tlen + i * BLKQ + w * 16 + m16) * (Hq * Dh)
                        + h * Dh + q8 * 4;
    #pragma unroll
    for (int dt = 0; dt < 8; ++dt) {
        union { u16x4 v; __hip_bfloat16 e[4]; } u;
        #pragma unroll
        for (int r = 0; r < 4; ++r)
            u.e[r] = __float2bfloat16(o[dt][r] * rcp);
        *(u16x4*)(op + dt * 16) = u.v;
    }
}

extern "C" void kernel_launch(void* const* d_in, const int* in_sizes, int n_in,
                              void* d_out, int out_size, void* d_ws, size_t ws_size,
                              hipStream_t stream) {
    const float* hs   = (const float*)d_in[0];
    const float* cosb = (const float*)d_in[1];
    const float* sinb = (const float*)d_in[2];
    const float* Wq   = (const float*)d_in[3];
    const float* Wk   = (const float*)d_in[4];
    const float* Wv   = (const float*)d_in[5];
    const float* Wo   = (const float*)d_in[6];

    const int M = Bsz * Tlen;                 // 8192
    const int nHS = M * HID;
    const int nWq = Hq * Dh * HID;
    const int nWk = HKV * Dh * HID;
    const int nWv = nWk;
    const int nWo = HID * Hq * Dh;

    // ws layout (bf16): hs | Wq | Wk | Wv | Wo | qkv | attn | vtg
    __hip_bfloat16* hsb  = (__hip_bfloat16*)d_ws;
    __hip_bfloat16* wqb  = hsb + nHS;
    __hip_bfloat16* wkb  = wqb + nWq;
    __hip_bfloat16* wvb  = wkb + nWk;
    __hip_bfloat16* wob  = wvb + nWv;
    __hip_bfloat16* qkv  = wob + nWo;               // [8192][3072]
    __hip_bfloat16* attn = qkv + (size_t)M * QKVC;  // [8192][2048]
    __hip_bfloat16* vtg  = attn + (size_t)M * (Hq * Dh);  // [8][128][4096]

    // 0) f32 -> bf16 conversion of hs + all weights
    cvt_kernel<<<dim3(8192, 5), 256, 0, stream>>>(
        hs, Wq, Wk, Wv, Wo, hsb, nHS, nWq, nWk, nWv, nWo);
    // 1) fused QKV projection + RoPE epilogue (bf16 out), 128sq eager-stage
    gemm128db<true, false><<<dim3(QKVC / 128, M / 128), 256, 0, stream>>>(
        hsb, wqb, wkb, wvb, HID, HID + 512, qkv, M, QKVC, HID, cosb, sinb);
    // 2) V pre-transpose for attention
    vtrans_kernel<<<dim3(NBLK, Bsz * HKV), 256, 0, stream>>>(qkv, vtg);
    // 3) block-sparse attention (bf16, swapped-QK in-register softmax)
    attn_kernel<<<dim3(NBLK, Hq, Bsz), 256, 0, stream>>>(qkv, vtg, attn);
    // 4) output projection (f32 out to d_out), 128sq eager-stage
    gemm128db<false, true><<<dim3(HID / 128, M / 128), 256, 0, stream>>>(
        attn, wob, wob, wob, HID, HID, d_out, M, HID, HID, nullptr, nullptr);
}